// Round 1
// baseline (324.762 us; speedup 1.0000x reference)
//
#include <hip/hip_runtime.h>

// FeatureTokenizer: out[b,c,h] = (x[b,c]*W[c,h] + b[c,h])*(1-m[b,c]) + me[h]*m[b,c]
// B=16384, C=128, H=128 -> 268,435,456 f32 outputs (1.07 GB). Write-bound.

constexpr int kB = 16384;
constexpr int kC = 128;
constexpr int kH = 128;
constexpr int kH4 = kH / 4;                 // 32 float4 per (b,c) row
constexpr int kTotal4 = kB * kC * kH4;      // 67,108,864 (< 2^31)

__global__ __launch_bounds__(256) void FeatureTokenizer_69664369541889_kernel(
    const float* __restrict__ x,      // (B, C)
    const float* __restrict__ m,      // (B, C)
    const float* __restrict__ W,      // (C, H)
    const float* __restrict__ bias,   // (C, H)
    const float* __restrict__ me,     // (1, H)
    float* __restrict__ out)          // (B, C, H)
{
    const float4* __restrict__ W4  = reinterpret_cast<const float4*>(W);
    const float4* __restrict__ b4  = reinterpret_cast<const float4*>(bias);
    const float4* __restrict__ me4 = reinterpret_cast<const float4*>(me);
    float4* __restrict__ out4      = reinterpret_cast<float4*>(out);

    const int stride = gridDim.x * blockDim.x;
    for (int idx = blockIdx.x * blockDim.x + threadIdx.x; idx < kTotal4; idx += stride) {
        const int h4 = idx & (kH4 - 1);       // which float4 along H
        const int rc = idx >> 5;              // row = b*C + c  (kH4 == 32)
        const int cc = rc & (kC - 1);         // c

        // 32 consecutive lanes share the same rc -> L1 broadcast.
        const float xv = x[rc];
        const float mv = m[rc];
        const float om = 1.0f - mv;

        const float4 w = W4[cc * kH4 + h4];   // 64 KB table, L2-resident
        const float4 bb = b4[cc * kH4 + h4];  // 64 KB table, L2-resident
        const float4 e = me4[h4];             // 512 B table

        float4 o;
        o.x = (xv * w.x + bb.x) * om + e.x * mv;
        o.y = (xv * w.y + bb.y) * om + e.y * mv;
        o.z = (xv * w.z + bb.z) * om + e.z * mv;
        o.w = (xv * w.w + bb.w) * om + e.w * mv;

        out4[idx] = o;
    }
}

extern "C" void kernel_launch(void* const* d_in, const int* in_sizes, int n_in,
                              void* d_out, int out_size, void* d_ws, size_t ws_size,
                              hipStream_t stream) {
    const float* x    = (const float*)d_in[0];  // x_numerical (B, C)
    const float* m    = (const float*)d_in[1];  // mask (B, C)
    const float* W    = (const float*)d_in[2];  // W (C, H)
    const float* bias = (const float*)d_in[3];  // b (C, H)
    const float* me   = (const float*)d_in[4];  // mask_embedding (1, H)
    float* out        = (float*)d_out;

    // Memory-bound: cap grid at ~2048 blocks, grid-stride the rest (G11).
    const int block = 256;
    const int grid = 2048;
    FeatureTokenizer_69664369541889_kernel<<<grid, block, 0, stream>>>(x, m, W, bias, me, out);
}

// Round 3
// 236.739 us; speedup vs baseline: 1.3718x; 1.3718x over previous
//
#include <hip/hip_runtime.h>

// FeatureTokenizer: out[b,c,h] = (x[b,c]*W[c,h] + b[c,h])*(1-m[b,c]) + me[h]*m[b,c]
// B=16384, C=128, H=128 -> 1.074 GB f32 output. Write-bandwidth-bound.
//
// Structure: grid*block = 524288 threads, 67,108,864 float4 outputs ->
// each thread does exactly 128 iterations with rc stepping by 16384
// (== 0 mod C). So (c, h4) is LOOP-INVARIANT per thread: hoist W/b/me
// loads; inner loop = {2 broadcast dword loads, FMAs, 1 NT 16B store},
// unrolled x4 for memory-level parallelism.

typedef float fx4 __attribute__((ext_vector_type(4)));  // native vec for NT store

constexpr int kB = 16384;
constexpr int kC = 128;
constexpr int kH = 128;
constexpr int kH4 = kH / 4;                    // 32 float4 per (b,c) row
constexpr int kTotal4 = kB * kC * kH4;         // 67,108,864
constexpr int kBlock = 256;
constexpr int kGrid = 2048;
constexpr int kStride4 = kGrid * kBlock;       // 524288 float4
constexpr int kIters = kTotal4 / kStride4;     // 128 (exact, no tail)
constexpr int kRcStep = kStride4 / kH4;        // 16384 rows (== 0 mod kC)

__global__ __launch_bounds__(kBlock) void FeatureTokenizer_69664369541889_kernel(
    const float* __restrict__ x,      // (B, C)
    const float* __restrict__ m,      // (B, C)
    const float* __restrict__ W,      // (C, H)
    const float* __restrict__ bias,   // (C, H)
    const float* __restrict__ me,     // (1, H)
    float* __restrict__ out)          // (B, C, H)
{
    const fx4* __restrict__ W4  = reinterpret_cast<const fx4*>(W);
    const fx4* __restrict__ b4  = reinterpret_cast<const fx4*>(bias);
    const fx4* __restrict__ me4 = reinterpret_cast<const fx4*>(me);
    fx4* __restrict__ out4      = reinterpret_cast<fx4*>(out);

    const int idx0 = blockIdx.x * kBlock + threadIdx.x;   // [0, 524288)
    const int h4   = idx0 & (kH4 - 1);
    int rc         = idx0 >> 5;                           // [0, 16384)
    const int cc   = rc & (kC - 1);                       // fixed per thread

    // Loop-invariant per-thread data (L2-resident tables).
    const fx4 w  = W4[cc * kH4 + h4];
    const fx4 bb = b4[cc * kH4 + h4];
    const fx4 e  = me4[h4];

    int oidx = idx0;
#pragma unroll 4
    for (int it = 0; it < kIters; ++it) {
        const float xv = x[rc];       // 32 lanes broadcast same dword
        const float mv = m[rc];
        const float om = 1.0f - mv;

        fx4 o;
        o.x = fmaf(fmaf(xv, w.x, bb.x), om, e.x * mv);
        o.y = fmaf(fmaf(xv, w.y, bb.y), om, e.y * mv);
        o.z = fmaf(fmaf(xv, w.z, bb.z), om, e.z * mv);
        o.w = fmaf(fmaf(xv, w.w, bb.w), om, e.w * mv);

        __builtin_nontemporal_store(o, &out4[oidx]);      // streaming write
        rc   += kRcStep;
        oidx += kStride4;
    }
}

extern "C" void kernel_launch(void* const* d_in, const int* in_sizes, int n_in,
                              void* d_out, int out_size, void* d_ws, size_t ws_size,
                              hipStream_t stream) {
    const float* x    = (const float*)d_in[0];  // x_numerical (B, C)
    const float* m    = (const float*)d_in[1];  // mask (B, C)
    const float* W    = (const float*)d_in[2];  // W (C, H)
    const float* bias = (const float*)d_in[3];  // b (C, H)
    const float* me   = (const float*)d_in[4];  // mask_embedding (1, H)
    float* out        = (float*)d_out;

    FeatureTokenizer_69664369541889_kernel<<<kGrid, kBlock, 0, stream>>>(x, m, W, bias, me, out);
}

// Round 4
// 233.408 us; speedup vs baseline: 1.3914x; 1.0143x over previous
//
#include <hip/hip_runtime.h>

// FeatureTokenizer: out[b,c,h] = (x[b,c]*W[c,h] + b[c,h])*(1-m[b,c]) + me[h]*m[b,c]
// B=16384, C=128, H=128 -> 1.074 GB f32 output. Write-bandwidth-bound.
//
// R4: drop the nontemporal store (the 6.5 TB/s fill kernel uses regular
// stores; NT bypasses the proven L2 writeback path) and deepen the unroll
// to 8 for more outstanding loads/stores per thread.
//
// Structure: grid*block = 524288 threads, 67,108,864 float4 outputs ->
// each thread does exactly 128 iterations with rc stepping by 16384
// (== 0 mod C). (c, h4) is LOOP-INVARIANT per thread: W/b/me hoisted.

typedef float fx4 __attribute__((ext_vector_type(4)));

constexpr int kB = 16384;
constexpr int kC = 128;
constexpr int kH = 128;
constexpr int kH4 = kH / 4;                    // 32 float4 per (b,c) row
constexpr int kTotal4 = kB * kC * kH4;         // 67,108,864
constexpr int kBlock = 256;
constexpr int kGrid = 2048;
constexpr int kStride4 = kGrid * kBlock;       // 524288 float4
constexpr int kIters = kTotal4 / kStride4;     // 128 (exact, no tail)
constexpr int kRcStep = kStride4 / kH4;        // 16384 rows (== 0 mod kC)

__global__ __launch_bounds__(kBlock) void FeatureTokenizer_69664369541889_kernel(
    const float* __restrict__ x,      // (B, C)
    const float* __restrict__ m,      // (B, C)
    const float* __restrict__ W,      // (C, H)
    const float* __restrict__ bias,   // (C, H)
    const float* __restrict__ me,     // (1, H)
    float* __restrict__ out)          // (B, C, H)
{
    const fx4* __restrict__ W4  = reinterpret_cast<const fx4*>(W);
    const fx4* __restrict__ b4  = reinterpret_cast<const fx4*>(bias);
    const fx4* __restrict__ me4 = reinterpret_cast<const fx4*>(me);
    fx4* __restrict__ out4      = reinterpret_cast<fx4*>(out);

    const int idx0 = blockIdx.x * kBlock + threadIdx.x;   // [0, 524288)
    const int h4   = idx0 & (kH4 - 1);
    int rc         = idx0 >> 5;                           // [0, 16384)
    const int cc   = rc & (kC - 1);                       // fixed per thread

    // Loop-invariant per-thread data (L2-resident tables).
    const fx4 w  = W4[cc * kH4 + h4];
    const fx4 bb = b4[cc * kH4 + h4];
    const fx4 e  = me4[h4];

    int oidx = idx0;
#pragma unroll 8
    for (int it = 0; it < kIters; ++it) {
        const float xv = x[rc];       // 32 lanes broadcast same dword
        const float mv = m[rc];
        const float om = 1.0f - mv;

        fx4 o;
        o.x = fmaf(fmaf(xv, w.x, bb.x), om, e.x * mv);
        o.y = fmaf(fmaf(xv, w.y, bb.y), om, e.y * mv);
        o.z = fmaf(fmaf(xv, w.z, bb.z), om, e.z * mv);
        o.w = fmaf(fmaf(xv, w.w, bb.w), om, e.w * mv);

        out4[oidx] = o;               // regular store: proven 6.5 TB/s path
        rc   += kRcStep;
        oidx += kStride4;
    }
}

extern "C" void kernel_launch(void* const* d_in, const int* in_sizes, int n_in,
                              void* d_out, int out_size, void* d_ws, size_t ws_size,
                              hipStream_t stream) {
    const float* x    = (const float*)d_in[0];  // x_numerical (B, C)
    const float* m    = (const float*)d_in[1];  // mask (B, C)
    const float* W    = (const float*)d_in[2];  // W (C, H)
    const float* bias = (const float*)d_in[3];  // b (C, H)
    const float* me   = (const float*)d_in[4];  // mask_embedding (1, H)
    float* out        = (float*)d_out;

    FeatureTokenizer_69664369541889_kernel<<<kGrid, kBlock, 0, stream>>>(x, m, W, bias, me, out);
}